// Round 1
// baseline (170.319 us; speedup 1.0000x reference)
//
#include <hip/hip_runtime.h>
#include <hip/hip_bf16.h>

typedef __attribute__((ext_vector_type(8))) short short8;
typedef __attribute__((ext_vector_type(4))) float f32x4;

static constexpr int MT = 32768;  // rows (N in reference)
static constexpr int KT = 256;    // contraction
static constexpr int CT = 4096;   // classes

// round-to-nearest-even float -> bf16 bits
__device__ __forceinline__ unsigned short f2b(float f) {
  unsigned int b = __float_as_uint(f);
  b += 0x7FFFu + ((b >> 16) & 1u);
  return (unsigned short)(b >> 16);
}

__global__ void __launch_bounds__(256) cvtA_kernel(const float* __restrict__ A,
                                                   unsigned short* __restrict__ Abf) {
  int i = blockIdx.x * 256 + threadIdx.x;  // one float4 each
  const float4 v = reinterpret_cast<const float4*>(A)[i];
  ushort4 o;
  o.x = f2b(v.x); o.y = f2b(v.y); o.z = f2b(v.z); o.w = f2b(v.w);
  reinterpret_cast<ushort4*>(Abf)[i] = o;
}

// B [KT][CT] fp32 -> Bt [CT][KT] bf16 (LDS-tiled transpose)
__global__ void __launch_bounds__(1024) cvtB_kernel(const float* __restrict__ B,
                                                    unsigned short* __restrict__ Bt) {
  __shared__ unsigned short tile[32][33];
  int tx = threadIdx.x & 31, ty = threadIdx.x >> 5;
  int c0 = blockIdx.x * 32, k0 = blockIdx.y * 32;
  tile[ty][tx] = f2b(B[(size_t)(k0 + ty) * CT + c0 + tx]);
  __syncthreads();
  Bt[(size_t)(c0 + ty) * KT + k0 + tx] = tile[tx][ty];
}

__device__ __forceinline__ void gload16(const void* g, void* l) {
  __builtin_amdgcn_global_load_lds(
      (const __attribute__((address_space(1))) void*)g,
      (__attribute__((address_space(3))) void*)l, 16, 0, 0);
}

__global__ void __launch_bounds__(256) gemm_kernel(const unsigned short* __restrict__ Abf,
                                                   const unsigned short* __restrict__ Btw,
                                                   float* __restrict__ O) {
  constexpr int BM = 128, BN = 128, BK = 32;
  __shared__ __align__(16) unsigned short Al[BM * BK];  // [m][k], 8 KB
  __shared__ __align__(16) unsigned short Bl[BN * BK];  // [c][k], 8 KB

  int bid = blockIdx.x;
  // XCD-aware swizzle; 8192 % 8 == 0 so the simple form is bijective
  int wg = (bid & 7) * (8192 / 8) + (bid >> 3);
  int tc = wg & 31;   // 32 col tiles
  int tr = wg >> 5;   // 256 row tiles
  int r0 = tr * BM, c0 = tc * BN;

  int tid = threadIdx.x;
  int lane = tid & 63, wid = tid >> 6;
  int wr = wid >> 1, wc = wid & 1;      // 2x2 waves, each owns 64x64
  int l15 = lane & 15, l4 = lane >> 4;

  f32x4 acc[4][4] = {};

  const int rowA = tid >> 2;            // 0..63 within a 64-row half
  const int kofs = (tid & 3) * 8;       // ushort offset within 32-wide K slab

  for (int t = 0; t < KT / BK; ++t) {
    if (t) __syncthreads();
#pragma unroll
    for (int j = 0; j < 2; ++j) {
      gload16(Abf + (size_t)(r0 + j * 64 + rowA) * KT + t * BK + kofs,
              Al + j * 2048 + wid * 512);
      gload16(Btw + (size_t)(c0 + j * 64 + rowA) * KT + t * BK + kofs,
              Bl + j * 2048 + wid * 512);
    }
    __syncthreads();  // drains vmcnt before barrier

    short8 af[4], bf[4];
#pragma unroll
    for (int m = 0; m < 4; ++m)
      af[m] = *reinterpret_cast<const short8*>(Al + (wr * 64 + m * 16 + l15) * BK + l4 * 8);
#pragma unroll
    for (int n = 0; n < 4; ++n)
      bf[n] = *reinterpret_cast<const short8*>(Bl + (wc * 64 + n * 16 + l15) * BK + l4 * 8);
#pragma unroll
    for (int m = 0; m < 4; ++m)
#pragma unroll
      for (int n = 0; n < 4; ++n)
        acc[m][n] = __builtin_amdgcn_mfma_f32_16x16x32_bf16(af[m], bf[n], acc[m][n], 0, 0, 0);
  }

  const float s = 1.0f / 16.0f;
#pragma unroll
  for (int m = 0; m < 4; ++m)
#pragma unroll
    for (int n = 0; n < 4; ++n) {
      size_t base = (size_t)(r0 + wr * 64 + m * 16 + l4 * 4) * CT +
                    (c0 + wc * 64 + n * 16 + l15);
#pragma unroll
      for (int j = 0; j < 4; ++j)
        O[base + (size_t)j * CT] = acc[m][n][j] * s;
    }
}

// Correct-but-slow insurance path if ws_size is too small for the bf16 copies.
__global__ void __launch_bounds__(256) naive_kernel(const float* __restrict__ A,
                                                    const float* __restrict__ B,
                                                    float* __restrict__ O) {
  size_t i = (size_t)blockIdx.x * 256 + threadIdx.x;
  int col = (int)(i & (size_t)(CT - 1));
  int row = (int)(i >> 12);
  float s = 0.f;
  for (int k = 0; k < KT; ++k)
    s += A[(size_t)row * KT + k] * B[(size_t)k * CT + col];
  O[i] = s * (1.0f / 16.0f);
}

extern "C" void kernel_launch(void* const* d_in, const int* in_sizes, int n_in,
                              void* d_out, int out_size, void* d_ws, size_t ws_size,
                              hipStream_t stream) {
  const float* A = (const float*)d_in[0];
  const float* B = (const float*)d_in[1];
  float* O = (float*)d_out;
  const size_t needA = (size_t)MT * KT * sizeof(unsigned short);  // 16 MiB
  const size_t needB = (size_t)CT * KT * sizeof(unsigned short);  //  2 MiB
  if (ws_size >= needA + needB) {
    unsigned short* Abf = (unsigned short*)d_ws;
    unsigned short* Btw = (unsigned short*)((char*)d_ws + needA);
    cvtA_kernel<<<MT * KT / 4 / 256, 256, 0, stream>>>(A, Abf);
    cvtB_kernel<<<dim3(CT / 32, KT / 32), 1024, 0, stream>>>(B, Btw);
    gemm_kernel<<<(MT / 128) * (CT / 128), 256, 0, stream>>>(Abf, Btw, O);
  } else {
    naive_kernel<<<(unsigned)((size_t)MT * CT / 256), 256, 0, stream>>>(A, B, O);
  }
}